// Round 16
// baseline (357.174 us; speedup 1.0000x reference)
//
#include <hip/hip_runtime.h>
#include <math.h>

typedef unsigned short u16;
typedef short s16;
typedef u16 u16x8 __attribute__((ext_vector_type(8)));
typedef s16 short8v __attribute__((ext_vector_type(8)));
typedef float f32x4 __attribute__((ext_vector_type(4)));

__device__ __forceinline__ float b2f(u16 u) {
    return __uint_as_float(((unsigned)u) << 16);
}
__device__ __forceinline__ u16 f2b(float f) {        // RNE
    unsigned u = __float_as_uint(f);
    unsigned r = (u + 0x7FFFu + ((u >> 16) & 1u)) >> 16;
    return (u16)r;
}

// ---------------------------------------------------------------------------
// bf16 table conversion: emb/wch/wrh plain + w2h PERMUTED
// (k' = (py*10+px)*8 + oc  <-  k = oc*100 + py*10+px), one launch.
// ---------------------------------------------------------------------------
__global__ __launch_bounds__(256) void k_cvt_all(
    const float* __restrict__ emb, u16* __restrict__ embh,
    const float* __restrict__ wcf, u16* __restrict__ wch,
    const float* __restrict__ wrf, u16* __restrict__ wrh,
    const float* __restrict__ w2f, u16* __restrict__ w2h)
{
    long j = (long)blockIdx.x * 256 + threadIdx.x;
    if (j < 1056400) {
        float4 v = ((const float4*)emb)[j];
        *(ushort4*)(embh + j * 4) = make_ushort4(f2b(v.x), f2b(v.y), f2b(v.z), f2b(v.w));
        return;
    }
    j -= 1056400;
    if (j < 7500) {
        float4 v = ((const float4*)wcf)[j];
        *(ushort4*)(wch + j * 4) = make_ushort4(f2b(v.x), f2b(v.y), f2b(v.z), f2b(v.w));
        return;
    }
    j -= 7500;
    if (j < 7500) {
        float4 v = ((const float4*)wrf)[j];
        *(ushort4*)(wrh + j * 4) = make_ushort4(f2b(v.x), f2b(v.y), f2b(v.z), f2b(v.w));
        return;
    }
    j -= 7500;
    if (j < 120000) {
        int jj = (int)(j / 800), k = (int)(j % 800);
        int p = k >> 3, oc = k & 7;
        w2h[jj * 800 + k] = f2b(w2f[jj * 800 + oc * 100 + p]);
    }
}

// ---------------------------------------------------------------------------
// Both vocab projections in one launch; both outputs bf16 (stride 152 shorts).
// ---------------------------------------------------------------------------
__global__ __launch_bounds__(256) void k_projmm2(
    const u16* __restrict__ embh, const u16* __restrict__ wc,
    const u16* __restrict__ wr, const float* __restrict__ bc,
    const float* __restrict__ br, u16* __restrict__ outc,
    u16* __restrict__ outr, int V)
{
    __shared__ s16 Ab[2048];      // [kc4][row64][e8]
    __shared__ s16 Bb[2560];      // [kc4][col80][e8]
    __shared__ float bhL[160];
    const int t = threadIdx.x;
    const int w = t >> 6, l = t & 63, lg = l >> 4, lr = l & 15;
    int id = blockIdx.x;
    const int half = (id >= 662) ? 1 : 0;
    id -= half * 662;
    const u16* wh = half ? wr : wc;
    const float* bias = half ? br : bc;
    u16* outp = half ? outr : outc;
    const int mb = id >> 1, nb = id & 1;
    const long rowbase = (long)mb * 64;
    const int colbase = nb * 80;
    if (t < 160) bhL[t] = (t < 150) ? bias[t] : 0.f;

    f32x4 acc[5];
#pragma unroll
    for (int i = 0; i < 5; ++i) acc[i] = (f32x4){0,0,0,0};

    for (int ch = 0; ch < 7; ++ch) {
        __syncthreads();
        {
            int row = t >> 2, kc = t & 3;        // coalesced: 4 lanes/row
            long grow = rowbase + row; if (grow >= V) grow = V - 1;
            int k0 = ch * 32 + kc * 8;
            short8v v = {0,0,0,0,0,0,0,0};
            if (k0 < 200) v = *(const short8v*)(embh + grow * 200 + k0);
            *(short8v*)&Ab[(kc * 64 + row) * 8] = v;
        }
        for (int it = t; it < 320; it += 256) {
            int col = it >> 2, kc = it & 3;      // coalesced
            int gcol = colbase + col;
            int k0 = ch * 32 + kc * 8;
            short8v v = {0,0,0,0,0,0,0,0};
            if (gcol < 150 && k0 < 200)
                v = *(const short8v*)(wh + (size_t)gcol * 200 + k0);
            *(short8v*)&Bb[(kc * 80 + col) * 8] = v;
        }
        __syncthreads();
        short8v a = *(short8v*)&Ab[(lg * 64 + w * 16 + lr) * 8];
#pragma unroll
        for (int ct = 0; ct < 5; ++ct) {
            short8v bv = *(short8v*)&Bb[(lg * 80 + ct * 16 + lr) * 8];
            acc[ct] = __builtin_amdgcn_mfma_f32_16x16x32_bf16(a, bv, acc[ct], 0, 0, 0);
        }
    }
#pragma unroll
    for (int ct = 0; ct < 5; ++ct) {
        int gcol = colbase + ct * 16 + lr;
        if (gcol < 150) {
#pragma unroll
            for (int rr = 0; rr < 4; ++rr) {
                long row = rowbase + w * 16 + lg * 4 + rr;
                outp[row * 152 + gcol] = f2b(acc[ct][rr] + bhL[gcol]);
            }
        }
    }
}

// ---------------------------------------------------------------------------
// GRU scan body on caller-provided LDS. MFMA GEMV; Whh B-frags in registers.
// ---------------------------------------------------------------------------
template<int MODE, int SEQS>
__device__ __forceinline__ void gru_body(
    char* sm, const void* __restrict__ xp_, const int* __restrict__ idx,
    const float* __restrict__ Whh, const float* __restrict__ bhh,
    void* __restrict__ hs_, int T, long blk)
{
    s16*   hbuf = (s16*)sm;                              // [1024]
    float* ghL  = (float*)(sm + 2048);                   // [SEQS*160]
    float* hL   = (float*)(sm + 2048 + SEQS * 640);      // [SEQS*52]
    float* bhL  = (float*)(sm + 2048 + SEQS * 848);      // [152]
    u16*   xraw = (u16*)(sm + 2048 + SEQS * 848 + 608);  // 9728 B
    const int t = threadIdx.x;
    const int w = t >> 6, l = t & 63, lg = l >> 4, lr = l & 15;
    constexpr int HST = (MODE == 2) ? 56 : 50;
    constexpr int XROW = SEQS * 152;
    u16*   xbH = xraw;
    float* xbF = (float*)xraw;

    for (int li = t; li < 1024; li += 256) hbuf[li] = 0;
    for (int e = t; e < SEQS * 52; e += 256) hL[e] = 0.f;
    if (t < 152) bhL[t] = (t < 150) ? bhh[t] : 0.f;

    const int te_0 = (w * 3     > 9) ? 9 : w * 3;
    const int te_1 = (w * 3 + 1 > 9) ? 9 : w * 3 + 1;
    const int te_2 = (w * 3 + 2 > 9) ? 9 : w * 3 + 2;
    short8v B00 = {0,0,0,0,0,0,0,0}, B01 = B00, B10 = B00, B11 = B00, B20 = B00, B21 = B00;
    {
        int cols[3] = { te_0 * 16 + lr, te_1 * 16 + lr, te_2 * 16 + lr };
        short8v* frg[6] = { &B00, &B01, &B10, &B11, &B20, &B21 };
#pragma unroll
        for (int ti = 0; ti < 3; ++ti) {
            int col = cols[ti];
            if (col < 150) {
#pragma unroll
                for (int s = 0; s < 2; ++s) {
                    short8v v = {0,0,0,0,0,0,0,0};
#pragma unroll
                    for (int e = 0; e < 8; ++e) {
                        int k = (s * 4 + lg) * 8 + e;
                        if (k < 50) v[e] = (s16)f2b(Whh[col * 50 + k]);
                    }
                    *frg[ti * 2 + s] = v;
                }
            }
        }
    }

    const long seqbase = blk * SEQS;
    const float* xpf = (const float*)xp_;
    const u16*   xph = (const u16*)xp_;
    float* hsf = (float*)hs_;
    u16*   hsh = (u16*)hs_;

    const int rA = (MODE == 2) ? t / 19 : t / 38;
    const int oA = (MODE == 2) ? (t % 19) * 8 : (t % 38) * 4;
    const int rB = (MODE == 2) ? (t + 256) / 19 : (t + 256) / 38;
    const int oB = (MODE == 2) ? ((t + 256) % 19) * 8 : ((t + 256) % 38) * 4;
    const bool actA = (MODE == 2) ? (t < SEQS * 19) : true;
    const bool hasB = (MODE == 2) ? (t + 256 < SEQS * 19) : (t + 256 < SEQS * 38);

    auto rowbase = [&](int rr, int stp) -> size_t {
        long r = seqbase + rr;
        long src = (MODE == 0) ? (r * T + stp) : (long)idx[r * T + stp];
        return (size_t)src * 152;
    };

    if (MODE == 2) {
        if (actA) *(u16x8*)&xbH[rA * 152 + oA] = *(const u16x8*)(xph + rowbase(rA, 0) + oA);
        if (hasB) *(u16x8*)&xbH[rB * 152 + oB] = *(const u16x8*)(xph + rowbase(rB, 0) + oB);
    } else {
        *(float4*)&xbF[rA * 152 + oA] = *(const float4*)(xpf + rowbase(rA, 0) + oA);
        if (hasB)
            *(float4*)&xbF[rB * 152 + oB] = *(const float4*)(xpf + rowbase(rB, 0) + oB);
    }
    __syncthreads();

    for (int st = 0; st < T; ++st) {
        const int cur = st & 1;
        u16x8 pfh0, pfh1;
        float4 pf0, pf1;
        if (st + 1 < T) {
            if (MODE == 2) {
                if (actA) pfh0 = *(const u16x8*)(xph + rowbase(rA, st + 1) + oA);
                if (hasB) pfh1 = *(const u16x8*)(xph + rowbase(rB, st + 1) + oB);
            } else {
                pf0 = *(const float4*)(xpf + rowbase(rA, st + 1) + oA);
                if (hasB) pf1 = *(const float4*)(xpf + rowbase(rB, st + 1) + oB);
            }
        }
        short8v a0 = *(short8v*)&hbuf[((0 + lg) * 16 + lr) * 8];
        short8v a1 = *(short8v*)&hbuf[((4 + lg) * 16 + lr) * 8];
        f32x4 c0 = {0,0,0,0}, c1 = {0,0,0,0}, c2 = {0,0,0,0};
        c0 = __builtin_amdgcn_mfma_f32_16x16x32_bf16(a0, B00, c0, 0, 0, 0);
        c0 = __builtin_amdgcn_mfma_f32_16x16x32_bf16(a1, B01, c0, 0, 0, 0);
        c1 = __builtin_amdgcn_mfma_f32_16x16x32_bf16(a0, B10, c1, 0, 0, 0);
        c1 = __builtin_amdgcn_mfma_f32_16x16x32_bf16(a1, B11, c1, 0, 0, 0);
        c2 = __builtin_amdgcn_mfma_f32_16x16x32_bf16(a0, B20, c2, 0, 0, 0);
        c2 = __builtin_amdgcn_mfma_f32_16x16x32_bf16(a1, B21, c2, 0, 0, 0);
        if (lg * 4 < SEQS) {
            int col0 = te_0 * 16 + lr, col1 = te_1 * 16 + lr, col2 = te_2 * 16 + lr;
            if (col0 < 150) {
#pragma unroll
                for (int r = 0; r < 4; ++r) ghL[(lg * 4 + r) * 160 + col0] = c0[r] + bhL[col0];
            }
            if (col1 < 150) {
#pragma unroll
                for (int r = 0; r < 4; ++r) ghL[(lg * 4 + r) * 160 + col1] = c1[r] + bhL[col1];
            }
            if (col2 < 150) {
#pragma unroll
                for (int r = 0; r < 4; ++r) ghL[(lg * 4 + r) * 160 + col2] = c2[r] + bhL[col2];
            }
        }
        __syncthreads();
        if (st + 1 < T) {
            if (MODE == 2) {
                if (actA) *(u16x8*)&xbH[(cur ^ 1) * XROW + rA * 152 + oA] = pfh0;
                if (hasB) *(u16x8*)&xbH[(cur ^ 1) * XROW + rB * 152 + oB] = pfh1;
            } else {
                *(float4*)&xbF[(cur ^ 1) * XROW + rA * 152 + oA] = pf0;
                if (hasB) *(float4*)&xbF[(cur ^ 1) * XROW + rB * 152 + oB] = pf1;
            }
        }
        for (int item = t; item < SEQS * 50; item += 256) {
            int ss = item / 50, hh = item % 50;
            float xv0, xv1, xv2;
            if (MODE == 2) {
                const u16* xr = &xbH[cur * XROW + ss * 152];
                xv0 = b2f(xr[hh]); xv1 = b2f(xr[50 + hh]); xv2 = b2f(xr[100 + hh]);
            } else {
                const float* xr = &xbF[cur * XROW + ss * 152];
                xv0 = xr[hh]; xv1 = xr[50 + hh]; xv2 = xr[100 + hh];
            }
            float vr  = xv0 + ghL[ss * 160 + hh];
            float vz  = xv1 + ghL[ss * 160 + 50 + hh];
            float ghn = ghL[ss * 160 + 100 + hh];
            float rg = 1.f / (1.f + __expf(-vr));
            float zg = 1.f / (1.f + __expf(-vz));
            float a = xv2 + rg * ghn;
            a = fminf(fmaxf(a, -15.f), 15.f);
            float e2 = __expf(-2.f * a);
            float nn2 = (1.f - e2) / (1.f + e2);
            float hn = (1.f - zg) * nn2 + zg * hL[ss * 52 + hh];
            hL[ss * 52 + hh] = hn;
            hbuf[((hh >> 3) * 16 + ss) * 8 + (hh & 7)] = (s16)f2b(hn);
            size_t ofs = ((size_t)(seqbase + ss) * T + st) * HST + hh;
            if (MODE == 2) hsh[ofs] = f2b(hn); else hsf[ofs] = hn;
        }
        __syncthreads();
    }
}

// ---------------------------------------------------------------------------
// matA tail for ctx-scan blocks: ctxA rows [blk*512, blk*512+512).
// Reads this block's own ctx_hh writes (same CU -> same L2). LDS reused.
// ---------------------------------------------------------------------------
__device__ __forceinline__ void matA_tail(
    char* sm, const u16* __restrict__ ctx_hh, const float* __restrict__ A,
    u16* __restrict__ ctxA_h, long blk)
{
    float* AL  = (float*)sm;            // [50][52] = 10400 B
    float* inL = (float*)(sm + 10400);  // [32][52] = 6656 B
    const int t = threadIdx.x;
    for (int e = t; e < 2500; e += 256) AL[(e / 50) * 52 + (e % 50)] = A[e];
    const long rbase0 = blk * 512;
    for (int c16 = 0; c16 < 16; ++c16) {
        __syncthreads();
        const long rbase = rbase0 + c16 * 32;
        for (int e = t; e < 1600; e += 256) {
            int r = e / 50, j = e % 50;
            inL[r * 52 + j] = b2f(ctx_hh[(rbase + r) * 56 + j]);
        }
        __syncthreads();
        for (int item = t; item < 1600; item += 256) {
            int r = item / 50, kk = item % 50;
            float acc = 0.f;
#pragma unroll 10
            for (int j = 0; j < 50; ++j)
                acc += inL[r * 52 + j] * AL[j * 52 + kk];
            ctxA_h[(rbase + r) * 56 + kk] = f2b(acc);
        }
    }
}

// ---------------------------------------------------------------------------
// Conv+pool epilogue (single-pass, 912-row convL): pool16 @0, wL @18960.
// ---------------------------------------------------------------------------
__device__ __forceinline__ void conv_pool_epi(
    char* sm, u16* __restrict__ feats, long nl, f32x4 cacc0, f32x4 cacc1)
{
    s16* pool16 = (s16*)sm;
    float* wL = (float*)(sm + 18960);
    u16* Mb    = (u16*)pool16;        // [2][1092], row stride 33
    u16* convL = (u16*)pool16 + 2184; // [912][8]
    const int t = threadIdx.x;
    const int w = t >> 6, l = t & 63, lg = l >> 4, lr = l & 15;
    const int job0 = w * 2, job1 = w * 2 + 1;
    const int ch0 = job0 >> 2, rt0 = (job0 >> 1) & 1, ct0 = job0 & 1;
    const int ch1 = job1 >> 2, rt1 = (job1 >> 1) & 1, ct1 = job1 & 1;

    __syncthreads();   // staging reads done; safe to alias with Mb
#pragma unroll
    for (int rr = 0; rr < 4; ++rr) {
        Mb[ch0 * 1092 + (rt0 * 16 + lg * 4 + rr) * 33 + ct0 * 16 + lr] = f2b(cacc0[rr]);
        Mb[ch1 * 1092 + (rt1 * 16 + lg * 4 + rr) * 33 + ct1 * 16 + lr] = f2b(cacc1[rr]);
    }

    short8v Bc = {0,0,0,0,0,0,0,0};
    int dlt[8];
#pragma unroll
    for (int e = 0; e < 8; ++e) {
        int s = lg * 8 + e;
        if (s < 18) {
            int ch = s / 9, r9 = s % 9, ky = r9 / 3, kx = r9 % 3;
            dlt[e] = ch * 1092 + ky * 33 + kx;
            if (lr < 8) Bc[e] = (s16)f2b(wL[lr * 18 + s]);
        } else dlt[e] = 0;
    }
    __syncthreads();   // Mb visible

    for (int tile = w; tile < 57; tile += 4) {
        int m = tile * 16 + lr;
        int cy = m / 30, cx = m - cy * 30;
        int base = cy * 33 + cx;
        short8v a;
#pragma unroll
        for (int e = 0; e < 8; ++e) a[e] = (s16)Mb[base + dlt[e]];
        f32x4 c = {0,0,0,0};
        c = __builtin_amdgcn_mfma_f32_16x16x32_bf16(a, Bc, c, 0, 0, 0);
        if (lr < 8) {
#pragma unroll
            for (int rr = 0; rr < 4; ++rr)
                convL[(tile * 16 + lg * 4 + rr) * 8 + lr] = f2b(c[rr]);
        }
    }
    __syncthreads();

    if (t < 100) {
        int py = t / 10, px = t % 10;
        int m0 = (3 * py) * 30 + 3 * px;
        float mx[8];
#pragma unroll
        for (int c = 0; c < 8; ++c) mx[c] = -1e30f;
#pragma unroll
        for (int dy = 0; dy < 3; ++dy)
#pragma unroll
            for (int dx = 0; dx < 3; ++dx) {
                u16x8 v = *(u16x8*)&convL[(m0 + dy * 30 + dx) * 8];
#pragma unroll
                for (int c = 0; c < 8; ++c) mx[c] = fmaxf(mx[c], b2f(v[c]));
            }
        u16x8 o;
#pragma unroll
        for (int c = 0; c < 8; ++c) o[c] = f2b(mx[c]);
        *(u16x8*)(feats + nl * 800 + t * 8) = o;
    }
}

// ---------------------------------------------------------------------------
// Conv+pool epilogue, two-half convL (464 rows), for the slim M2 kernel.
// ---------------------------------------------------------------------------
__device__ __forceinline__ void conv_pool_epi2(
    s16* pool, short8v Bc, const int* dlt,
    u16* __restrict__ feats, long nl, f32x4 cacc0, f32x4 cacc1)
{
    u16* Mb    = (u16*)pool;          // [2][1092], row stride 33
    u16* convL = (u16*)pool + 2184;   // [464][8]
    const int t = threadIdx.x;
    const int w = t >> 6, l = t & 63, lg = l >> 4, lr = l & 15;
    const int job0 = w * 2, job1 = w * 2 + 1;
    const int ch0 = job0 >> 2, rt0 = (job0 >> 1) & 1, ct0 = job0 & 1;
    const int ch1 = job1 >> 2, rt1 = (job1 >> 1) & 1, ct1 = job1 & 1;

    __syncthreads();   // all staging reads done; safe to alias
#pragma unroll
    for (int rr = 0; rr < 4; ++rr) {
        Mb[ch0 * 1092 + (rt0 * 16 + lg * 4 + rr) * 33 + ct0 * 16 + lr] = f2b(cacc0[rr]);
        Mb[ch1 * 1092 + (rt1 * 16 + lg * 4 + rr) * 33 + ct1 * 16 + lr] = f2b(cacc1[rr]);
    }
    __syncthreads();   // Mb visible

    for (int tile = w; tile < 29; tile += 4) {
        int m = tile * 16 + lr;
        int cy = m / 30, cx = m - cy * 30;
        int base = cy * 33 + cx;
        short8v a;
#pragma unroll
        for (int e = 0; e < 8; ++e) a[e] = (s16)Mb[base + dlt[e]];
        f32x4 c = {0,0,0,0};
        c = __builtin_amdgcn_mfma_f32_16x16x32_bf16(a, Bc, c, 0, 0, 0);
        if (lr < 8) {
#pragma unroll
            for (int rr = 0; rr < 4; ++rr)
                convL[(tile * 16 + lg * 4 + rr) * 8 + lr] = f2b(c[rr]);
        }
    }
    __syncthreads();
    if (t < 50) {
        int py = t / 10, px = t % 10;
        int m0 = (3 * py) * 30 + 3 * px;
        float mx[8];
#pragma unroll
        for (int c = 0; c < 8; ++c) mx[c] = -1e30f;
#pragma unroll
        for (int dy = 0; dy < 3; ++dy)
#pragma unroll
            for (int dx = 0; dx < 3; ++dx) {
                u16x8 v = *(u16x8*)&convL[(m0 + dy * 30 + dx) * 8];
#pragma unroll
                for (int c = 0; c < 8; ++c) mx[c] = fmaxf(mx[c], b2f(v[c]));
            }
        u16x8 o;
#pragma unroll
        for (int c = 0; c < 8; ++c) o[c] = f2b(mx[c]);
        *(u16x8*)(feats + nl * 800 + t * 8) = o;
    }
    __syncthreads();
    for (int tile = 28 + w; tile < 57; tile += 4) {
        int m = tile * 16 + lr;
        int cy = m / 30, cx = m - cy * 30;
        int base = cy * 33 + cx;
        short8v a;
#pragma unroll
        for (int e = 0; e < 8; ++e) a[e] = (s16)Mb[base + dlt[e]];
        f32x4 c = {0,0,0,0};
        c = __builtin_amdgcn_mfma_f32_16x16x32_bf16(a, Bc, c, 0, 0, 0);
        if (lr < 8) {
#pragma unroll
            for (int rr = 0; rr < 4; ++rr)
                convL[(tile * 16 + lg * 4 + rr - 448) * 8 + lr] = f2b(c[rr]);
        }
    }
    __syncthreads();
    if (t < 50) {
        int py = 5 + t / 10, px = t % 10;
        int m0 = (3 * py) * 30 + 3 * px - 448;
        float mx[8];
#pragma unroll
        for (int c = 0; c < 8; ++c) mx[c] = -1e30f;
#pragma unroll
        for (int dy = 0; dy < 3; ++dy)
#pragma unroll
            for (int dx = 0; dx < 3; ++dx) {
                u16x8 v = *(u16x8*)&convL[(m0 + dy * 30 + dx) * 8];
#pragma unroll
                for (int c = 0; c < 8; ++c) mx[c] = fmaxf(mx[c], b2f(v[c]));
            }
        u16x8 o;
#pragma unroll
        for (int c = 0; c < 8; ++c) o[c] = f2b(mx[c]);
        *(u16x8*)(feats + nl * 800 + (50 + t) * 8) = o;
    }
    __syncthreads();
}

// ---------------------------------------------------------------------------
// M1 body: one block per slot n = b*14 + r, r<7; coalesced gather staging.
// LDS: pool16 @0, wL @18960, ci @19536, qi @19664.
// ---------------------------------------------------------------------------
__device__ __forceinline__ void m1_body(
    char* sm, const u16* __restrict__ embh, const int* __restrict__ ctx_idx,
    const int* __restrict__ cand_idx, const float* __restrict__ conv_w,
    u16* __restrict__ feats, int wg)
{
    s16* pool16 = (s16*)sm;
    float* wL = (float*)(sm + 18960);
    int* ci = (int*)(sm + 19536);
    int* qi = (int*)(sm + 19664);     // [2][32]
    const int t = threadIdx.x;
    const int xcd = wg & 7, q = wg >> 3;
    const int r = q % 7, bq = q / 7;
    const int b = bq * 8 + xcd;
    const long nl = (long)b * 14 + r;
    const int w = t >> 6, l = t & 63, lg = l >> 4, lr = l & 15;

    if (t < 144) wL[t] = conv_w[t];

    f32x4 cacc0 = {0,0,0,0}, cacc1 = {0,0,0,0};
    const int job0 = w * 2, job1 = w * 2 + 1;
    const int ch0 = job0 >> 2, rt0 = (job0 >> 1) & 1, ct0 = job0 & 1;
    const int ch1 = job1 >> 2, rt1 = (job1 >> 1) & 1, ct1 = job1 & 1;

    const int c0 = 2 * r;
    if (t < 32) ci[t] = ctx_idx[b * 32 + t];
    else if (t < 96)
        qi[((t - 32) >> 5) * 32 + (t & 31)] =
            cand_idx[((long)b * 14 + c0 + ((t - 32) >> 5)) * 32 + (t & 31)];
    __syncthreads();
    s16* ctxL = pool16;            // [kc<=12][33][8]
    s16* canL = pool16 + 3168;     // [kc<=12][65][8]
#pragma unroll
    for (int cnk = 0; cnk < 3; ++cnk) {
        const int kcbase = (cnk == 0) ? 0 : (cnk == 1 ? 12 : 20);
        const int kccnt  = (cnk == 0) ? 12 : 8;
        const int scnt   = (cnk == 0) ? 3 : 2;
        if (cnk) __syncthreads();
        for (int it = t; it < kccnt * 32; it += 256) {
            int row = it / kccnt, kcl = it - row * kccnt;   // coalesced gather
            int kc = kcbase + kcl;
            short8v v = {0,0,0,0,0,0,0,0};
            if (kc < 25) v = *(const short8v*)(embh + (size_t)ci[row] * 200 + kc * 8);
            *(short8v*)&ctxL[(kcl * 33 + row) * 8] = v;
        }
        for (int it = t; it < kccnt * 64; it += 256) {
            int col = it / kccnt, kcl = it - col * kccnt;   // coalesced gather
            int kc = kcbase + kcl;
            short8v v = {0,0,0,0,0,0,0,0};
            if (kc < 25)
                v = *(const short8v*)(embh + (size_t)qi[(col >> 5) * 32 + (col & 31)] * 200 + kc * 8);
            *(short8v*)&canL[(kcl * 65 + col) * 8] = v;
        }
        __syncthreads();
        for (int sl = 0; sl < scnt; ++sl) {
            int kcl = sl * 4 + lg;
            short8v a0 = *(short8v*)&ctxL[(kcl * 33 + rt0 * 16 + lr) * 8];
            short8v b0 = *(short8v*)&canL[(kcl * 65 + ch0 * 32 + ct0 * 16 + lr) * 8];
            short8v b1 = *(short8v*)&canL[(kcl * 65 + ch1 * 32 + ct1 * 16 + lr) * 8];
            cacc0 = __builtin_amdgcn_mfma_f32_16x16x32_bf16(a0, b0, cacc0, 0, 0, 0);
            short8v a1 = (rt0 == rt1) ? a0
                       : *(short8v*)&ctxL[(kcl * 33 + rt1 * 16 + lr) * 8];
            cacc1 = __builtin_amdgcn_mfma_f32_16x16x32_bf16(a1, b1, cacc1, 0, 0, 0);
        }
    }
    conv_pool_epi(sm, feats, nl, cacc0, cacc1);
}

// ---------------------------------------------------------------------------
// Merged launch: 0..895 cand-scan, 896..959 ctx-scan (+matA tail), 960.. M1.
// ---------------------------------------------------------------------------
__global__ __launch_bounds__(256) void k_scan_m1(
    const u16* __restrict__ proj_ch, const u16* __restrict__ proj_rh,
    const int* __restrict__ ctx_idx, const int* __restrict__ cand_idx,
    const float* __restrict__ Whh_c, const float* __restrict__ Whh_r,
    const float* __restrict__ bhh_c, const float* __restrict__ bhh_r,
    u16* __restrict__ ctx_hh, u16* __restrict__ candh_h,
    const u16* __restrict__ embh, const float* __restrict__ conv_w,
    u16* __restrict__ feats, const float* __restrict__ A,
    u16* __restrict__ ctxA_h)
{
    __shared__ long long smq[3244];   // 25952 B unified pool
    char* sm = (char*)smq;
    const long bid = blockIdx.x;
    if (bid < 960) {
        const bool cand = (bid < 896);
        gru_body<2, 16>(sm,
                        cand ? (const void*)proj_rh : (const void*)proj_ch,
                        cand ? cand_idx : ctx_idx,
                        cand ? Whh_r : Whh_c,
                        cand ? bhh_r : bhh_c,
                        cand ? (void*)candh_h : (void*)ctx_hh,
                        32, cand ? bid : bid - 896);
        if (!cand) matA_tail(sm, ctx_hh, A, ctxA_h, bid - 896);
    } else {
        m1_body(sm, embh, ctx_idx, cand_idx, conv_w, feats, (int)(bid - 960));
    }
}

// ---------------------------------------------------------------------------
// xp2 body, r-tiled: xp2 rows n = (btile*64+row)*14 + rr for one rr.
// LDS: Ab @0 (4096B), Bb @4096 (5120B), bhL @9216 (640B).
// ---------------------------------------------------------------------------
__device__ __forceinline__ void xp2_body(
    char* sm, const u16* __restrict__ feats, const u16* __restrict__ w2h,
    const float* __restrict__ bih2, float* __restrict__ out, int id2, int rlo)
{
    s16* Ab = (s16*)sm;               // [kc4][row64][e8]
    s16* Bb = (s16*)sm + 4608;        // [kc4][col80][e8]  (4608 s16 = 9216 B off)
    float* bhL = (float*)(sm + 14336);
    const int t = threadIdx.x;
    const int w = t >> 6, l = t & 63, lg = l >> 4, lr = l & 15;
    const int btile = id2 / 14, rem = id2 % 14;
    const int rr = rlo + rem / 2, nb = rem % 2;
    const int colbase = nb * 80;
    if (t < 160) bhL[t] = (t < 150) ? bih2[t] : 0.f;

    f32x4 acc[5];
#pragma unroll
    for (int i = 0; i < 5; ++i) acc[i] = (f32x4){0,0,0,0};

    for (int ch = 0; ch < 25; ++ch) {
        __syncthreads();
        {
            int row = t >> 2, kc = t & 3;    // coalesced: 4 lanes/row, 64B runs
            long n = ((long)btile * 64 + row) * 14 + rr;
            *(short8v*)&Ab[(kc * 64 + row) * 8] =
                *(const short8v*)(feats + n * 800 + ch * 32 + kc * 8);
        }
        for (int it = t; it < 320; it += 256) {
            int col = it >> 2, kc = it & 3;  // coalesced
            int gcol = colbase + col;
            short8v v = {0,0,0,0,0,0,0,0};
            if (gcol < 150)
                v = *(const short8v*)(w2h + (size_t)gcol * 800 + ch * 32 + kc * 8);
            *(short8v*)&Bb[(kc * 80 + col) * 8] = v;
        }
        __syncthreads();
        short8v a = *(short8v*)&Ab[(lg * 64 + w * 16 + lr) * 8];
#pragma unroll
        for (int ct = 0; ct < 5; ++ct) {
            short8v bv = *(short8v*)&Bb[(lg * 80 + ct * 16 + lr) * 8];
            acc[ct] = __builtin_amdgcn_mfma_f32_16x16x32_bf16(a, bv, acc[ct], 0, 0, 0);
        }
    }
#pragma unroll
    for (int ct = 0; ct < 5; ++ct) {
        int gcol = colbase + ct * 16 + lr;
        if (gcol < 150) {
#pragma unroll
            for (int rr4 = 0; rr4 < 4; ++rr4) {
                long n = ((long)btile * 64 + w * 16 + lg * 4 + rr4) * 14 + rr;
                out[n * 152 + gcol] = acc[ct][rr4] + bhL[gcol];
            }
        }
    }
}

// ---------------------------------------------------------------------------
// Merged M2 + xp2(M1 rows): bid<7168 -> M2 match+conv+pool; else xp2 r<7.
// LDS 14976 B (shared).
// ---------------------------------------------------------------------------
__global__ __launch_bounds__(256) void k_m2x(
    const u16* __restrict__ ctxA_h, const u16* __restrict__ candh_h,
    const float* __restrict__ conv_w, u16* __restrict__ feats,
    const u16* __restrict__ w2h, const float* __restrict__ bih2,
    float* __restrict__ xp2)
{
    __shared__ long long smq[1872];   // 14976 B
    char* sm = (char*)smq;
    const int bid = blockIdx.x;
    if (bid >= 7168) {
        xp2_body(sm, feats, w2h, bih2, xp2, bid - 7168, 0);
        return;
    }
    s16* aL = (s16*)sm;               // [8][33][8]
    s16* cL = (s16*)sm + 2112;        // [8][65][8]
    float* wL = (float*)(sm + 12544);
    const int t = threadIdx.x;
    const int xcd = bid & 7, q = bid >> 3;
    const int r7 = q % 7, bq = q / 7;
    const int b = bq * 8 + xcd;
    const long nl = (long)b * 14 + 7 + r7;
    const int w = t >> 6, l = t & 63, lg = l >> 4, lr = l & 15;

    if (t < 144) wL[t] = conv_w[t];

    f32x4 cacc0 = {0,0,0,0}, cacc1 = {0,0,0,0};
    const int job0 = w * 2, job1 = w * 2 + 1;
    const int ch0 = job0 >> 2, rt0 = (job0 >> 1) & 1, ct0 = job0 & 1;
    const int ch1 = job1 >> 2, rt1 = (job1 >> 1) & 1, ct1 = job1 & 1;

    const int c0 = 2 * r7;
    for (int it = t; it < 256; it += 256) {
        int row = it >> 3, kc = it & 7;      // coalesced gather
        short8v v = {0,0,0,0,0,0,0,0};
        if (kc < 7) {
            v = *(const short8v*)(ctxA_h + (size_t)(b * 32 + row) * 56 + kc * 8);
            if (kc == 6) { v[2] = 0; v[3] = 0; v[4] = 0; v[5] = 0; v[6] = 0; v[7] = 0; }
        }
        *(short8v*)&aL[(kc * 33 + row) * 8] = v;
    }
    for (int it = t; it < 512; it += 256) {
        int col = it >> 3, kc = it & 7;      // coalesced gather
        long row = ((long)b * 14 + c0 + (col >> 5)) * 32 + (col & 31);
        short8v v = {0,0,0,0,0,0,0,0};
        if (kc < 7) {
            v = *(const short8v*)(candh_h + (size_t)row * 56 + kc * 8);
            if (kc == 6) { v[2] = 0; v[3] = 0; v[4] = 0; v[5] = 0; v[6] = 0; v[7] = 0; }
        }
        *(short8v*)&cL[(kc * 65 + col) * 8] = v;
    }
    __syncthreads();

    short8v Bc = {0,0,0,0,0,0,0,0};
    int dlt[8];
#pragma unroll
    for (int e = 0; e < 8; ++e) {
        int s = lg * 8 + e;
        if (s < 18) {
            int ch = s / 9, r9 = s % 9, ky = r9 / 3, kx = r9 % 3;
            dlt[e] = ch * 1092 + ky * 33 + kx;
            if (lr < 8) Bc[e] = (s16)f2b(wL[lr * 18 + s]);
        } else dlt[e] = 0;
    }

#pragma unroll
    for (int sl = 0; sl < 2; ++sl) {
        int kcl = sl * 4 + lg;
        short8v a0 = *(short8v*)&aL[(kcl * 33 + rt0 * 16 + lr) * 8];
        short8v b0 = *(short8v*)&cL[(kcl * 65 + ch0 * 32 + ct0 * 16 + lr) * 8];
        short8v b1 = *(short8v*)&cL[(kcl * 65 + ch1 * 32 + ct1 * 16 + lr) * 8];
        cacc0 = __builtin_amdgcn_mfma_f32_16x16x32_bf16(a0, b0, cacc0, 0, 0, 0);
        short8v a1 = (rt0 == rt1) ? a0
                   : *(short8v*)&aL[(kcl * 33 + rt1 * 16 + lr) * 8];
        cacc1 = __builtin_amdgcn_mfma_f32_16x16x32_bf16(a1, b1, cacc1, 0, 0, 0);
    }
    conv_pool_epi2((s16*)sm, Bc, dlt, feats, nl, cacc0, cacc1);
}

// xp2 for M2 rows (r in [7,14)): grid 224.
__global__ __launch_bounds__(256) void k_xp2t(
    const u16* __restrict__ feats, const u16* __restrict__ w2h,
    const float* __restrict__ bih2, float* __restrict__ xp2)
{
    __shared__ long long smq[1872];
    xp2_body((char*)smq, feats, w2h, bih2, xp2, (int)blockIdx.x, 7);
}

// GRU2 scan: direct fp32 xp2, fp32 hs2.
__global__ __launch_bounds__(256) void k_scan2(
    const float* __restrict__ xp2, const float* __restrict__ Whh2,
    const float* __restrict__ bhh2, float* __restrict__ hs2)
{
    __shared__ long long smq[2396];   // 19168 B
    gru_body<0, 8>((char*)smq, xp2, nullptr, Whh2, bhh2, hs2, 14, (long)blockIdx.x);
}

// ---------------------------------------------------------------------------
// fc1 + fc2 + log_softmax + KL fused: one block per b.
// ---------------------------------------------------------------------------
__global__ __launch_bounds__(128) void k_head(
    const float* __restrict__ Hs, const float* __restrict__ w1,
    const float* __restrict__ b1, const float* __restrict__ w2,
    const float* __restrict__ b2, const float* __restrict__ y,
    float* __restrict__ partial)
{
    __shared__ float hr[700];
    __shared__ float hidL[100];
    const int t = threadIdx.x;
    const long b = blockIdx.x;
    for (int e = t; e < 700; e += 128) hr[e] = Hs[b * 700 + e];
    __syncthreads();
    if (t < 100) {
        float acc = b1[t];
        const float4* wp = (const float4*)(w1 + (size_t)t * 700);
        for (int k4 = 0; k4 < 175; ++k4) {
            float4 wv = wp[k4];
            float4 hv = *(float4*)&hr[k4 * 4];
            acc += wv.x * hv.x + wv.y * hv.y + wv.z * hv.z + wv.w * hv.w;
        }
        hidL[t] = fmaxf(acc, 0.f);
    }
    __syncthreads();
    if (t < 64) {
        float logit = -1e30f;
        if (t < 14) {
            logit = b2[t];
            for (int k = 0; k < 100; ++k) logit += hidL[k] * w2[t * 100 + k];
        }
        float m = logit;
        for (int off = 8; off; off >>= 1) m = fmaxf(m, __shfl_xor(m, off, 16));
        float ex = (t < 14) ? __expf(logit - m) : 0.f;
        float se = ex;
        for (int off = 8; off; off >>= 1) se += __shfl_xor(se, off, 16);
        float kl = 0.f;
        if (t < 14) {
            float lp = logit - m - __logf(se);
            float yv = y[b * 14 + t];
            kl = (yv > 0.f) ? yv * (__logf(yv) - lp) : 0.f;
        }
        for (int off = 8; off; off >>= 1) kl += __shfl_xor(kl, off, 16);
        if (t == 0) partial[b] = kl;
    }
}

__global__ __launch_bounds__(256) void k_reduce(
    const float* __restrict__ partial, float* __restrict__ out)
{
    __shared__ float sm[256];
    const int t = threadIdx.x;
    sm[t] = partial[t] + partial[t + 256] + partial[t + 512] + partial[t + 768];
    __syncthreads();
    for (int off = 128; off; off >>= 1) {
        if (t < off) sm[t] += sm[t + off];
        __syncthreads();
    }
    if (t == 0) out[0] = sm[0] * (1.f / 14336.f);
}

// ---------------------------------------------------------------------------
extern "C" void kernel_launch(void* const* d_in, const int* in_sizes, int n_in,
                              void* d_out, int out_size, void* d_ws, size_t ws_size,
                              hipStream_t stream)
{
    const int*   ctx_idx  = (const int*)d_in[0];
    const int*   cand_idx = (const int*)d_in[1];
    const float* y_dev    = (const float*)d_in[2];
    const float* emb      = (const float*)d_in[3];
    const float* A        = (const float*)d_in[4];
    const float* Wih_c    = (const float*)d_in[5];
    const float* Whh_c    = (const float*)d_in[6];
    const float* bih_c    = (const float*)d_in[7];
    const float* bhh_c    = (const float*)d_in[8];
    const float* Wih_r    = (const float*)d_in[9];
    const float* Whh_r    = (const float*)d_in[10];
    const float* bih_r    = (const float*)d_in[11];
    const float* bhh_r    = (const float*)d_in[12];
    const float* conv_w   = (const float*)d_in[13];
    const float* Wih2     = (const float*)d_in[14];
    const float* Whh2     = (const float*)d_in[15];
    const float* bih2     = (const float*)d_in[16];
    const float* bhh2     = (const float*)d_in[17];
    const float* fc1_w    = (const float*)d_in[18];
    const float* fc1_b    = (const float*)d_in[19];
    const float* fc2_w    = (const float*)d_in[20];
    const float* fc2_b    = (const float*)d_in[21];

    float* ws = (float*)d_ws;
    // Arena (float slots), total 28,734,128 f = 114.9 MB. All regions disjoint.
    u16*   embh    = (u16*)ws;               // [21128][200] bf16 = 2,112,800 f
    u16*   proj_ch = (u16*)(ws + 2112800);   // [21184][152] bf16 = 1,609,984 f
    u16*   proj_rh = (u16*)(ws + 3722784);   // [21184][152] bf16 = 1,609,984 f
    u16*   ctx_hh  = (u16*)(ws + 5332768);   // [32768][56] bf16 = 917,504 f
    u16*   ctxA_h  = (u16*)(ws + 6250272);   // [32768][56] bf16 = 917,504 f
    u16*   candh_h = (u16*)(ws + 7167776);   // [458752][56] bf16 = 12,845,056 f
    u16*   feats_h = (u16*)(ws + 20012832);  // [14336][800] bf16 = 5,734,400 f
    u16*   w2h     = (u16*)(ws + 25747232);  // [150][800] bf16 = 60,000 f
    u16*   wch     = (u16*)(ws + 25807232);  // [150][200] bf16 = 15,000 f
    u16*   wrh     = (u16*)(ws + 25822232);  // [150][200] bf16 = 15,000 f
    float* xp2     = ws + 25837232;          // [14336][152] = 2,179,072
    float* hs2     = ws + 28016304;          // 716,800
    float* part    = ws + 28733104;          // 1,024

    // 0. bf16 tables (one launch; w2h stored k-permuted)
    k_cvt_all <<<4654, 256, 0, stream>>>(emb, embh, Wih_c, wch, Wih_r, wrh,
                                         Wih2, w2h);
    // 1. both vocab projections (one launch, bih folded, bf16 out)
    k_projmm2 <<<1324, 256, 0, stream>>>(embh, wch, wrh, bih_c, bih_r,
                                         proj_ch, proj_rh, 21128);
    // 2. merged: GRU scans (960; ctx blocks also compute ctxA) + M1 (7168)
    k_scan_m1 <<<8128, 256, 0, stream>>>(proj_ch, proj_rh, ctx_idx, cand_idx,
                                         Whh_c, Whh_r, bhh_c, bhh_r,
                                         ctx_hh, candh_h, embh, conv_w, feats_h,
                                         A, ctxA_h);
    // 3. M2 match+conv+pool (7168) + xp2 for M1 rows (224), one launch
    k_m2x <<<7392, 256, 0, stream>>>(ctxA_h, candh_h, conv_w, feats_h,
                                     w2h, bih2, xp2);
    // 4. xp2 for M2 rows, GRU2, fused head
    k_xp2t <<<224, 256, 0, stream>>>(feats_h, w2h, bih2, xp2);
    k_scan2 <<<128, 256, 0, stream>>>(xp2, Whh2, bhh2, hs2);
    k_head <<<1024, 128, 0, stream>>>(hs2, fc1_w, fc1_b, fc2_w, fc2_b, y_dev, part);
    k_reduce <<<1, 256, 0, stream>>>(part, (float*)d_out);
}

// Round 17
// 305.080 us; speedup vs baseline: 1.1708x; 1.1708x over previous
//
#include <hip/hip_runtime.h>
#include <math.h>

typedef unsigned short u16;
typedef short s16;
typedef u16 u16x8 __attribute__((ext_vector_type(8)));
typedef s16 short8v __attribute__((ext_vector_type(8)));
typedef float f32x4 __attribute__((ext_vector_type(4)));

__device__ __forceinline__ float b2f(u16 u) {
    return __uint_as_float(((unsigned)u) << 16);
}
__device__ __forceinline__ u16 f2b(float f) {        // RNE
    unsigned u = __float_as_uint(f);
    unsigned r = (u + 0x7FFFu + ((u >> 16) & 1u)) >> 16;
    return (u16)r;
}

// ---------------------------------------------------------------------------
// bf16 table conversion: emb/wch/wrh plain + w2h PERMUTED
// (k' = (py*10+px)*8 + oc  <-  k = oc*100 + py*10+px), one launch.
// ---------------------------------------------------------------------------
__global__ __launch_bounds__(256) void k_cvt_all(
    const float* __restrict__ emb, u16* __restrict__ embh,
    const float* __restrict__ wcf, u16* __restrict__ wch,
    const float* __restrict__ wrf, u16* __restrict__ wrh,
    const float* __restrict__ w2f, u16* __restrict__ w2h)
{
    long j = (long)blockIdx.x * 256 + threadIdx.x;
    if (j < 1056400) {
        float4 v = ((const float4*)emb)[j];
        *(ushort4*)(embh + j * 4) = make_ushort4(f2b(v.x), f2b(v.y), f2b(v.z), f2b(v.w));
        return;
    }
    j -= 1056400;
    if (j < 7500) {
        float4 v = ((const float4*)wcf)[j];
        *(ushort4*)(wch + j * 4) = make_ushort4(f2b(v.x), f2b(v.y), f2b(v.z), f2b(v.w));
        return;
    }
    j -= 7500;
    if (j < 7500) {
        float4 v = ((const float4*)wrf)[j];
        *(ushort4*)(wrh + j * 4) = make_ushort4(f2b(v.x), f2b(v.y), f2b(v.z), f2b(v.w));
        return;
    }
    j -= 7500;
    if (j < 120000) {
        int jj = (int)(j / 800), k = (int)(j % 800);
        int p = k >> 3, oc = k & 7;
        w2h[jj * 800 + k] = f2b(w2f[jj * 800 + oc * 100 + p]);
    }
}

// ---------------------------------------------------------------------------
// Both vocab projections in one launch; both outputs bf16 (stride 152 shorts).
// ---------------------------------------------------------------------------
__global__ __launch_bounds__(256) void k_projmm2(
    const u16* __restrict__ embh, const u16* __restrict__ wc,
    const u16* __restrict__ wr, const float* __restrict__ bc,
    const float* __restrict__ br, u16* __restrict__ outc,
    u16* __restrict__ outr, int V)
{
    __shared__ s16 Ab[2048];      // [kc4][row64][e8]
    __shared__ s16 Bb[2560];      // [kc4][col80][e8]
    __shared__ float bhL[160];
    const int t = threadIdx.x;
    const int w = t >> 6, l = t & 63, lg = l >> 4, lr = l & 15;
    int id = blockIdx.x;
    const int half = (id >= 662) ? 1 : 0;
    id -= half * 662;
    const u16* wh = half ? wr : wc;
    const float* bias = half ? br : bc;
    u16* outp = half ? outr : outc;
    const int mb = id >> 1, nb = id & 1;
    const long rowbase = (long)mb * 64;
    const int colbase = nb * 80;
    if (t < 160) bhL[t] = (t < 150) ? bias[t] : 0.f;

    f32x4 acc[5];
#pragma unroll
    for (int i = 0; i < 5; ++i) acc[i] = (f32x4){0,0,0,0};

    for (int ch = 0; ch < 7; ++ch) {
        __syncthreads();
        {
            int kc = t >> 6, row = t & 63;
            long grow = rowbase + row; if (grow >= V) grow = V - 1;
            int k0 = ch * 32 + kc * 8;
            short8v v = {0,0,0,0,0,0,0,0};
            if (k0 < 200) v = *(const short8v*)(embh + grow * 200 + k0);
            *(short8v*)&Ab[t * 8] = v;
        }
        for (int it = t; it < 320; it += 256) {
            int kc = it / 80, col = it % 80;
            int gcol = colbase + col;
            int k0 = ch * 32 + kc * 8;
            short8v v = {0,0,0,0,0,0,0,0};
            if (gcol < 150 && k0 < 200)
                v = *(const short8v*)(wh + (size_t)gcol * 200 + k0);
            *(short8v*)&Bb[it * 8] = v;
        }
        __syncthreads();
        short8v a = *(short8v*)&Ab[(lg * 64 + w * 16 + lr) * 8];
#pragma unroll
        for (int ct = 0; ct < 5; ++ct) {
            short8v bv = *(short8v*)&Bb[(lg * 80 + ct * 16 + lr) * 8];
            acc[ct] = __builtin_amdgcn_mfma_f32_16x16x32_bf16(a, bv, acc[ct], 0, 0, 0);
        }
    }
#pragma unroll
    for (int ct = 0; ct < 5; ++ct) {
        int gcol = colbase + ct * 16 + lr;
        if (gcol < 150) {
#pragma unroll
            for (int rr = 0; rr < 4; ++rr) {
                long row = rowbase + w * 16 + lg * 4 + rr;
                outp[row * 152 + gcol] = f2b(acc[ct][rr] + bhL[gcol]);
            }
        }
    }
}

// ---------------------------------------------------------------------------
// GRU scan body on caller-provided LDS. MFMA GEMV; Whh B-frags in registers.
// MODE 0: direct fp32 xp (stride 152), fp32 hs (50).
// MODE 2: gather bf16 xp via idx (stride 152), bf16 hs (stride 56).
// LDS bytes: 2048 + SEQS*848 + 608 + 9728.
// ---------------------------------------------------------------------------
template<int MODE, int SEQS>
__device__ __forceinline__ void gru_body(
    char* sm, const void* __restrict__ xp_, const int* __restrict__ idx,
    const float* __restrict__ Whh, const float* __restrict__ bhh,
    void* __restrict__ hs_, int T, long blk)
{
    s16*   hbuf = (s16*)sm;                              // [1024]
    float* ghL  = (float*)(sm + 2048);                   // [SEQS*160]
    float* hL   = (float*)(sm + 2048 + SEQS * 640);      // [SEQS*52]
    float* bhL  = (float*)(sm + 2048 + SEQS * 848);      // [152]
    u16*   xraw = (u16*)(sm + 2048 + SEQS * 848 + 608);  // 9728 B
    const int t = threadIdx.x;
    const int w = t >> 6, l = t & 63, lg = l >> 4, lr = l & 15;
    constexpr int HST = (MODE == 2) ? 56 : 50;
    constexpr int XROW = SEQS * 152;
    u16*   xbH = xraw;
    float* xbF = (float*)xraw;

    for (int li = t; li < 1024; li += 256) hbuf[li] = 0;
    for (int e = t; e < SEQS * 52; e += 256) hL[e] = 0.f;
    if (t < 152) bhL[t] = (t < 150) ? bhh[t] : 0.f;

    const int te_0 = (w * 3     > 9) ? 9 : w * 3;
    const int te_1 = (w * 3 + 1 > 9) ? 9 : w * 3 + 1;
    const int te_2 = (w * 3 + 2 > 9) ? 9 : w * 3 + 2;
    short8v B00 = {0,0,0,0,0,0,0,0}, B01 = B00, B10 = B00, B11 = B00, B20 = B00, B21 = B00;
    {
        int cols[3] = { te_0 * 16 + lr, te_1 * 16 + lr, te_2 * 16 + lr };
        short8v* frg[6] = { &B00, &B01, &B10, &B11, &B20, &B21 };
#pragma unroll
        for (int ti = 0; ti < 3; ++ti) {
            int col = cols[ti];
            if (col < 150) {
#pragma unroll
                for (int s = 0; s < 2; ++s) {
                    short8v v = {0,0,0,0,0,0,0,0};
#pragma unroll
                    for (int e = 0; e < 8; ++e) {
                        int k = (s * 4 + lg) * 8 + e;
                        if (k < 50) v[e] = (s16)f2b(Whh[col * 50 + k]);
                    }
                    *frg[ti * 2 + s] = v;
                }
            }
        }
    }

    const long seqbase = blk * SEQS;
    const float* xpf = (const float*)xp_;
    const u16*   xph = (const u16*)xp_;
    float* hsf = (float*)hs_;
    u16*   hsh = (u16*)hs_;

    const int rA = (MODE == 2) ? t / 19 : t / 38;
    const int oA = (MODE == 2) ? (t % 19) * 8 : (t % 38) * 4;
    const int rB = (MODE == 2) ? (t + 256) / 19 : (t + 256) / 38;
    const int oB = (MODE == 2) ? ((t + 256) % 19) * 8 : ((t + 256) % 38) * 4;
    const bool actA = (MODE == 2) ? (t < SEQS * 19) : true;
    const bool hasB = (MODE == 2) ? (t + 256 < SEQS * 19) : (t + 256 < SEQS * 38);

    auto rowbase = [&](int rr, int stp) -> size_t {
        long r = seqbase + rr;
        long src = (MODE == 0) ? (r * T + stp) : (long)idx[r * T + stp];
        return (size_t)src * 152;
    };

    if (MODE == 2) {
        if (actA) *(u16x8*)&xbH[rA * 152 + oA] = *(const u16x8*)(xph + rowbase(rA, 0) + oA);
        if (hasB) *(u16x8*)&xbH[rB * 152 + oB] = *(const u16x8*)(xph + rowbase(rB, 0) + oB);
    } else {
        *(float4*)&xbF[rA * 152 + oA] = *(const float4*)(xpf + rowbase(rA, 0) + oA);
        if (hasB)
            *(float4*)&xbF[rB * 152 + oB] = *(const float4*)(xpf + rowbase(rB, 0) + oB);
    }
    __syncthreads();

    for (int st = 0; st < T; ++st) {
        const int cur = st & 1;
        u16x8 pfh0, pfh1;
        float4 pf0, pf1;
        if (st + 1 < T) {
            if (MODE == 2) {
                if (actA) pfh0 = *(const u16x8*)(xph + rowbase(rA, st + 1) + oA);
                if (hasB) pfh1 = *(const u16x8*)(xph + rowbase(rB, st + 1) + oB);
            } else {
                pf0 = *(const float4*)(xpf + rowbase(rA, st + 1) + oA);
                if (hasB) pf1 = *(const float4*)(xpf + rowbase(rB, st + 1) + oB);
            }
        }
        short8v a0 = *(short8v*)&hbuf[((0 + lg) * 16 + lr) * 8];
        short8v a1 = *(short8v*)&hbuf[((4 + lg) * 16 + lr) * 8];
        f32x4 c0 = {0,0,0,0}, c1 = {0,0,0,0}, c2 = {0,0,0,0};
        c0 = __builtin_amdgcn_mfma_f32_16x16x32_bf16(a0, B00, c0, 0, 0, 0);
        c0 = __builtin_amdgcn_mfma_f32_16x16x32_bf16(a1, B01, c0, 0, 0, 0);
        c1 = __builtin_amdgcn_mfma_f32_16x16x32_bf16(a0, B10, c1, 0, 0, 0);
        c1 = __builtin_amdgcn_mfma_f32_16x16x32_bf16(a1, B11, c1, 0, 0, 0);
        c2 = __builtin_amdgcn_mfma_f32_16x16x32_bf16(a0, B20, c2, 0, 0, 0);
        c2 = __builtin_amdgcn_mfma_f32_16x16x32_bf16(a1, B21, c2, 0, 0, 0);
        if (lg * 4 < SEQS) {
            int col0 = te_0 * 16 + lr, col1 = te_1 * 16 + lr, col2 = te_2 * 16 + lr;
            if (col0 < 150) {
#pragma unroll
                for (int r = 0; r < 4; ++r) ghL[(lg * 4 + r) * 160 + col0] = c0[r] + bhL[col0];
            }
            if (col1 < 150) {
#pragma unroll
                for (int r = 0; r < 4; ++r) ghL[(lg * 4 + r) * 160 + col1] = c1[r] + bhL[col1];
            }
            if (col2 < 150) {
#pragma unroll
                for (int r = 0; r < 4; ++r) ghL[(lg * 4 + r) * 160 + col2] = c2[r] + bhL[col2];
            }
        }
        __syncthreads();
        if (st + 1 < T) {
            if (MODE == 2) {
                if (actA) *(u16x8*)&xbH[(cur ^ 1) * XROW + rA * 152 + oA] = pfh0;
                if (hasB) *(u16x8*)&xbH[(cur ^ 1) * XROW + rB * 152 + oB] = pfh1;
            } else {
                *(float4*)&xbF[(cur ^ 1) * XROW + rA * 152 + oA] = pf0;
                if (hasB) *(float4*)&xbF[(cur ^ 1) * XROW + rB * 152 + oB] = pf1;
            }
        }
        for (int item = t; item < SEQS * 50; item += 256) {
            int ss = item / 50, hh = item % 50;
            float xv0, xv1, xv2;
            if (MODE == 2) {
                const u16* xr = &xbH[cur * XROW + ss * 152];
                xv0 = b2f(xr[hh]); xv1 = b2f(xr[50 + hh]); xv2 = b2f(xr[100 + hh]);
            } else {
                const float* xr = &xbF[cur * XROW + ss * 152];
                xv0 = xr[hh]; xv1 = xr[50 + hh]; xv2 = xr[100 + hh];
            }
            float vr  = xv0 + ghL[ss * 160 + hh];
            float vz  = xv1 + ghL[ss * 160 + 50 + hh];
            float ghn = ghL[ss * 160 + 100 + hh];
            float rg = 1.f / (1.f + __expf(-vr));
            float zg = 1.f / (1.f + __expf(-vz));
            float a = xv2 + rg * ghn;
            a = fminf(fmaxf(a, -15.f), 15.f);
            float e2 = __expf(-2.f * a);
            float nn2 = (1.f - e2) / (1.f + e2);
            float hn = (1.f - zg) * nn2 + zg * hL[ss * 52 + hh];
            hL[ss * 52 + hh] = hn;
            hbuf[((hh >> 3) * 16 + ss) * 8 + (hh & 7)] = (s16)f2b(hn);
            size_t ofs = ((size_t)(seqbase + ss) * T + st) * HST + hh;
            if (MODE == 2) hsh[ofs] = f2b(hn); else hsf[ofs] = hn;
        }
        __syncthreads();
    }
}

// ---------------------------------------------------------------------------
// Conv+pool epilogue (single-pass, 912-row convL) on LDS layout:
// pool16 @0 (9480 s16), wL @18960. Used by M1 blocks.
// ---------------------------------------------------------------------------
__device__ __forceinline__ void conv_pool_epi(
    char* sm, u16* __restrict__ feats, long nl, f32x4 cacc0, f32x4 cacc1)
{
    s16* pool16 = (s16*)sm;
    float* wL = (float*)(sm + 18960);
    u16* Mb    = (u16*)pool16;        // [2][1092], row stride 33
    u16* convL = (u16*)pool16 + 2184; // [912][8]
    const int t = threadIdx.x;
    const int w = t >> 6, l = t & 63, lg = l >> 4, lr = l & 15;
    const int job0 = w * 2, job1 = w * 2 + 1;
    const int ch0 = job0 >> 2, rt0 = (job0 >> 1) & 1, ct0 = job0 & 1;
    const int ch1 = job1 >> 2, rt1 = (job1 >> 1) & 1, ct1 = job1 & 1;

    __syncthreads();   // staging reads done; safe to alias with Mb
#pragma unroll
    for (int rr = 0; rr < 4; ++rr) {
        Mb[ch0 * 1092 + (rt0 * 16 + lg * 4 + rr) * 33 + ct0 * 16 + lr] = f2b(cacc0[rr]);
        Mb[ch1 * 1092 + (rt1 * 16 + lg * 4 + rr) * 33 + ct1 * 16 + lr] = f2b(cacc1[rr]);
    }

    short8v Bc = {0,0,0,0,0,0,0,0};
    int dlt[8];
#pragma unroll
    for (int e = 0; e < 8; ++e) {
        int s = lg * 8 + e;
        if (s < 18) {
            int ch = s / 9, r9 = s % 9, ky = r9 / 3, kx = r9 % 3;
            dlt[e] = ch * 1092 + ky * 33 + kx;
            if (lr < 8) Bc[e] = (s16)f2b(wL[lr * 18 + s]);
        } else dlt[e] = 0;
    }
    __syncthreads();   // Mb visible

    for (int tile = w; tile < 57; tile += 4) {
        int m = tile * 16 + lr;
        int cy = m / 30, cx = m - cy * 30;
        int base = cy * 33 + cx;
        short8v a;
#pragma unroll
        for (int e = 0; e < 8; ++e) a[e] = (s16)Mb[base + dlt[e]];
        f32x4 c = {0,0,0,0};
        c = __builtin_amdgcn_mfma_f32_16x16x32_bf16(a, Bc, c, 0, 0, 0);
        if (lr < 8) {
#pragma unroll
            for (int rr = 0; rr < 4; ++rr)
                convL[(tile * 16 + lg * 4 + rr) * 8 + lr] = f2b(c[rr]);
        }
    }
    __syncthreads();

    if (t < 100) {
        int py = t / 10, px = t % 10;
        int m0 = (3 * py) * 30 + 3 * px;
        float mx[8];
#pragma unroll
        for (int c = 0; c < 8; ++c) mx[c] = -1e30f;
#pragma unroll
        for (int dy = 0; dy < 3; ++dy)
#pragma unroll
            for (int dx = 0; dx < 3; ++dx) {
                u16x8 v = *(u16x8*)&convL[(m0 + dy * 30 + dx) * 8];
#pragma unroll
                for (int c = 0; c < 8; ++c) mx[c] = fmaxf(mx[c], b2f(v[c]));
            }
        u16x8 o;
#pragma unroll
        for (int c = 0; c < 8; ++c) o[c] = f2b(mx[c]);
        *(u16x8*)(feats + nl * 800 + t * 8) = o;
    }
}

// ---------------------------------------------------------------------------
// Conv+pool epilogue, two-half convL (464 rows), for the slim M2 kernel.
// pool region >= 5896 s16: Mb [2][1092] @0, convL [464][8] @2184.
// ---------------------------------------------------------------------------
__device__ __forceinline__ void conv_pool_epi2(
    s16* pool, short8v Bc, const int* dlt,
    u16* __restrict__ feats, long nl, f32x4 cacc0, f32x4 cacc1)
{
    u16* Mb    = (u16*)pool;          // [2][1092], row stride 33
    u16* convL = (u16*)pool + 2184;   // [464][8]
    const int t = threadIdx.x;
    const int w = t >> 6, l = t & 63, lg = l >> 4, lr = l & 15;
    const int job0 = w * 2, job1 = w * 2 + 1;
    const int ch0 = job0 >> 2, rt0 = (job0 >> 1) & 1, ct0 = job0 & 1;
    const int ch1 = job1 >> 2, rt1 = (job1 >> 1) & 1, ct1 = job1 & 1;

    __syncthreads();   // all staging reads done; safe to alias
#pragma unroll
    for (int rr = 0; rr < 4; ++rr) {
        Mb[ch0 * 1092 + (rt0 * 16 + lg * 4 + rr) * 33 + ct0 * 16 + lr] = f2b(cacc0[rr]);
        Mb[ch1 * 1092 + (rt1 * 16 + lg * 4 + rr) * 33 + ct1 * 16 + lr] = f2b(cacc1[rr]);
    }
    __syncthreads();   // Mb visible

    for (int tile = w; tile < 29; tile += 4) {
        int m = tile * 16 + lr;
        int cy = m / 30, cx = m - cy * 30;
        int base = cy * 33 + cx;
        short8v a;
#pragma unroll
        for (int e = 0; e < 8; ++e) a[e] = (s16)Mb[base + dlt[e]];
        f32x4 c = {0,0,0,0};
        c = __builtin_amdgcn_mfma_f32_16x16x32_bf16(a, Bc, c, 0, 0, 0);
        if (lr < 8) {
#pragma unroll
            for (int rr = 0; rr < 4; ++rr)
                convL[(tile * 16 + lg * 4 + rr) * 8 + lr] = f2b(c[rr]);
        }
    }
    __syncthreads();
    if (t < 50) {
        int py = t / 10, px = t % 10;
        int m0 = (3 * py) * 30 + 3 * px;
        float mx[8];
#pragma unroll
        for (int c = 0; c < 8; ++c) mx[c] = -1e30f;
#pragma unroll
        for (int dy = 0; dy < 3; ++dy)
#pragma unroll
            for (int dx = 0; dx < 3; ++dx) {
                u16x8 v = *(u16x8*)&convL[(m0 + dy * 30 + dx) * 8];
#pragma unroll
                for (int c = 0; c < 8; ++c) mx[c] = fmaxf(mx[c], b2f(v[c]));
            }
        u16x8 o;
#pragma unroll
        for (int c = 0; c < 8; ++c) o[c] = f2b(mx[c]);
        *(u16x8*)(feats + nl * 800 + t * 8) = o;
    }
    __syncthreads();
    for (int tile = 28 + w; tile < 57; tile += 4) {
        int m = tile * 16 + lr;
        int cy = m / 30, cx = m - cy * 30;
        int base = cy * 33 + cx;
        short8v a;
#pragma unroll
        for (int e = 0; e < 8; ++e) a[e] = (s16)Mb[base + dlt[e]];
        f32x4 c = {0,0,0,0};
        c = __builtin_amdgcn_mfma_f32_16x16x32_bf16(a, Bc, c, 0, 0, 0);
        if (lr < 8) {
#pragma unroll
            for (int rr = 0; rr < 4; ++rr)
                convL[(tile * 16 + lg * 4 + rr - 448) * 8 + lr] = f2b(c[rr]);
        }
    }
    __syncthreads();
    if (t < 50) {
        int py = 5 + t / 10, px = t % 10;
        int m0 = (3 * py) * 30 + 3 * px - 448;
        float mx[8];
#pragma unroll
        for (int c = 0; c < 8; ++c) mx[c] = -1e30f;
#pragma unroll
        for (int dy = 0; dy < 3; ++dy)
#pragma unroll
            for (int dx = 0; dx < 3; ++dx) {
                u16x8 v = *(u16x8*)&convL[(m0 + dy * 30 + dx) * 8];
#pragma unroll
                for (int c = 0; c < 8; ++c) mx[c] = fmaxf(mx[c], b2f(v[c]));
            }
        u16x8 o;
#pragma unroll
        for (int c = 0; c < 8; ++c) o[c] = f2b(mx[c]);
        *(u16x8*)(feats + nl * 800 + (50 + t) * 8) = o;
    }
    __syncthreads();
}

// ---------------------------------------------------------------------------
// M1 body (round-13 structure): one block per slot n = b*14 + r, r<7.
// LDS: pool16 @0, wL @18960, ci @19536, qi @19664.
// ---------------------------------------------------------------------------
__device__ __forceinline__ void m1_body(
    char* sm, const u16* __restrict__ embh, const int* __restrict__ ctx_idx,
    const int* __restrict__ cand_idx, const float* __restrict__ conv_w,
    u16* __restrict__ feats, int wg)
{
    s16* pool16 = (s16*)sm;
    float* wL = (float*)(sm + 18960);
    int* ci = (int*)(sm + 19536);
    int* qi = (int*)(sm + 19664);     // [2][32]
    const int t = threadIdx.x;
    const int xcd = wg & 7, q = wg >> 3;
    const int r = q % 7, bq = q / 7;
    const int b = bq * 8 + xcd;
    const long nl = (long)b * 14 + r;
    const int w = t >> 6, l = t & 63, lg = l >> 4, lr = l & 15;

    if (t < 144) wL[t] = conv_w[t];

    f32x4 cacc0 = {0,0,0,0}, cacc1 = {0,0,0,0};
    const int job0 = w * 2, job1 = w * 2 + 1;
    const int ch0 = job0 >> 2, rt0 = (job0 >> 1) & 1, ct0 = job0 & 1;
    const int ch1 = job1 >> 2, rt1 = (job1 >> 1) & 1, ct1 = job1 & 1;

    const int c0 = 2 * r;
    if (t < 32) ci[t] = ctx_idx[b * 32 + t];
    else if (t < 96)
        qi[((t - 32) >> 5) * 32 + (t & 31)] =
            cand_idx[((long)b * 14 + c0 + ((t - 32) >> 5)) * 32 + (t & 31)];
    __syncthreads();
    s16* ctxL = pool16;            // [kc<=12][33][8]
    s16* canL = pool16 + 3168;     // [kc<=12][65][8]
#pragma unroll
    for (int cnk = 0; cnk < 3; ++cnk) {
        const int kcbase = (cnk == 0) ? 0 : (cnk == 1 ? 12 : 20);
        const int kccnt  = (cnk == 0) ? 12 : 8;
        const int scnt   = (cnk == 0) ? 3 : 2;
        if (cnk) __syncthreads();
        for (int it = t; it < kccnt * 32; it += 256) {
            int kcl = it >> 5, row = it & 31;
            int kc = kcbase + kcl;
            short8v v = {0,0,0,0,0,0,0,0};
            if (kc < 25) v = *(const short8v*)(embh + (size_t)ci[row] * 200 + kc * 8);
            *(short8v*)&ctxL[(kcl * 33 + row) * 8] = v;
        }
        for (int it = t; it < kccnt * 64; it += 256) {
            int kcl = it >> 6, col = it & 63;
            int kc = kcbase + kcl;
            short8v v = {0,0,0,0,0,0,0,0};
            if (kc < 25)
                v = *(const short8v*)(embh + (size_t)qi[(col >> 5) * 32 + (col & 31)] * 200 + kc * 8);
            *(short8v*)&canL[(kcl * 65 + col) * 8] = v;
        }
        __syncthreads();
        for (int sl = 0; sl < scnt; ++sl) {
            int kcl = sl * 4 + lg;
            short8v a0 = *(short8v*)&ctxL[(kcl * 33 + rt0 * 16 + lr) * 8];
            short8v b0 = *(short8v*)&canL[(kcl * 65 + ch0 * 32 + ct0 * 16 + lr) * 8];
            short8v b1 = *(short8v*)&canL[(kcl * 65 + ch1 * 32 + ct1 * 16 + lr) * 8];
            cacc0 = __builtin_amdgcn_mfma_f32_16x16x32_bf16(a0, b0, cacc0, 0, 0, 0);
            short8v a1 = (rt0 == rt1) ? a0
                       : *(short8v*)&ctxL[(kcl * 33 + rt1 * 16 + lr) * 8];
            cacc1 = __builtin_amdgcn_mfma_f32_16x16x32_bf16(a1, b1, cacc1, 0, 0, 0);
        }
    }
    conv_pool_epi(sm, feats, nl, cacc0, cacc1);
}

// ---------------------------------------------------------------------------
// Merged launch: blocks 0..895 cand-scan, 896..959 ctx-scan, 960.. M1 blocks.
// ---------------------------------------------------------------------------
__global__ __launch_bounds__(256) void k_scan_m1(
    const u16* __restrict__ proj_ch, const u16* __restrict__ proj_rh,
    const int* __restrict__ ctx_idx, const int* __restrict__ cand_idx,
    const float* __restrict__ Whh_c, const float* __restrict__ Whh_r,
    const float* __restrict__ bhh_c, const float* __restrict__ bhh_r,
    u16* __restrict__ ctx_hh, u16* __restrict__ candh_h,
    const u16* __restrict__ embh, const float* __restrict__ conv_w,
    u16* __restrict__ feats)
{
    __shared__ long long smq[3244];   // 25952 B unified pool
    char* sm = (char*)smq;
    const long bid = blockIdx.x;
    if (bid < 960) {
        const bool cand = (bid < 896);
        gru_body<2, 16>(sm,
                        cand ? (const void*)proj_rh : (const void*)proj_ch,
                        cand ? cand_idx : ctx_idx,
                        cand ? Whh_r : Whh_c,
                        cand ? bhh_r : bhh_c,
                        cand ? (void*)candh_h : (void*)ctx_hh,
                        32, cand ? bid : bid - 896);
    } else {
        m1_body(sm, embh, ctx_idx, cand_idx, conv_w, feats, (int)(bid - 960));
    }
}

// ---------------------------------------------------------------------------
// M2 kernel (slots n = b*14 + 7 + r, r<7): slim 13.1 KB LDS, 12 blocks/CU.
// aL [8][33][8] @0, cL [8][65][8] @2112 s16, epilogue aliases @0, wL @12544B.
// ---------------------------------------------------------------------------
__global__ __launch_bounds__(256) void k_m2conv(
    const u16* __restrict__ ctxA_h, const u16* __restrict__ candh_h,
    const float* __restrict__ conv_w, u16* __restrict__ feats)
{
    __shared__ long long smq[1640];   // 13120 B
    char* sm = (char*)smq;
    s16* aL = (s16*)sm;               // [8][33][8]
    s16* cL = (s16*)sm + 2112;        // [8][65][8]
    float* wL = (float*)(sm + 12544);
    const int t = threadIdx.x;
    const int wg = blockIdx.x;
    const int xcd = wg & 7, q = wg >> 3;
    const int r7 = q % 7, bq = q / 7;
    const int b = bq * 8 + xcd;
    const long nl = (long)b * 14 + 7 + r7;
    const int w = t >> 6, l = t & 63, lg = l >> 4, lr = l & 15;

    if (t < 144) wL[t] = conv_w[t];

    f32x4 cacc0 = {0,0,0,0}, cacc1 = {0,0,0,0};
    const int job0 = w * 2, job1 = w * 2 + 1;
    const int ch0 = job0 >> 2, rt0 = (job0 >> 1) & 1, ct0 = job0 & 1;
    const int ch1 = job1 >> 2, rt1 = (job1 >> 1) & 1, ct1 = job1 & 1;

    const int c0 = 2 * r7;
    for (int it = t; it < 256; it += 256) {
        int kc = it >> 5, row = it & 31;
        short8v v = {0,0,0,0,0,0,0,0};
        if (kc < 7) {
            v = *(const short8v*)(ctxA_h + (size_t)(b * 32 + row) * 56 + kc * 8);
            if (kc == 6) { v[2] = 0; v[3] = 0; v[4] = 0; v[5] = 0; v[6] = 0; v[7] = 0; }
        }
        *(short8v*)&aL[(kc * 33 + row) * 8] = v;
    }
    for (int it = t; it < 512; it += 256) {
        int kc = it >> 6, col = it & 63;
        long row = ((long)b * 14 + c0 + (col >> 5)) * 32 + (col & 31);
        short8v v = {0,0,0,0,0,0,0,0};
        if (kc < 7) {
            v = *(const short8v*)(candh_h + (size_t)row * 56 + kc * 8);
            if (kc == 6) { v[2] = 0; v[3] = 0; v[4] = 0; v[5] = 0; v[6] = 0; v[7] = 0; }
        }
        *(short8v*)&cL[(kc * 65 + col) * 8] = v;
    }
    __syncthreads();

    short8v Bc = {0,0,0,0,0,0,0,0};
    int dlt[8];
#pragma unroll
    for (int e = 0; e < 8; ++e) {
        int s = lg * 8 + e;
        if (s < 18) {
            int ch = s / 9, r9 = s % 9, ky = r9 / 3, kx = r9 % 3;
            dlt[e] = ch * 1092 + ky * 33 + kx;
            if (lr < 8) Bc[e] = (s16)f2b(wL[lr * 18 + s]);
        } else dlt[e] = 0;
    }

#pragma unroll
    for (int sl = 0; sl < 2; ++sl) {
        int kcl = sl * 4 + lg;
        short8v a0 = *(short8v*)&aL[(kcl * 33 + rt0 * 16 + lr) * 8];
        short8v b0 = *(short8v*)&cL[(kcl * 65 + ch0 * 32 + ct0 * 16 + lr) * 8];
        short8v b1 = *(short8v*)&cL[(kcl * 65 + ch1 * 32 + ct1 * 16 + lr) * 8];
        cacc0 = __builtin_amdgcn_mfma_f32_16x16x32_bf16(a0, b0, cacc0, 0, 0, 0);
        short8v a1 = (rt0 == rt1) ? a0
                   : *(short8v*)&aL[(kcl * 33 + rt1 * 16 + lr) * 8];
        cacc1 = __builtin_amdgcn_mfma_f32_16x16x32_bf16(a1, b1, cacc1, 0, 0, 0);
    }
    conv_pool_epi2((s16*)sm, Bc, dlt, feats, nl, cacc0, cacc1);
}

// GRU2 scan: direct fp32 xp2, fp32 hs2.
__global__ __launch_bounds__(256) void k_scan2(
    const float* __restrict__ xp2, const float* __restrict__ Whh2,
    const float* __restrict__ bhh2, float* __restrict__ hs2)
{
    __shared__ long long smq[2396];   // 19168 B
    gru_body<0, 8>((char*)smq, xp2, nullptr, Whh2, bhh2, hs2, 14, (long)blockIdx.x);
}

// ---------------------------------------------------------------------------
// ctxA[r][k] (bf16, stride 56) = sum_j b2f(ctx_hh[r][j]) * A[j][k]
// ---------------------------------------------------------------------------
__global__ __launch_bounds__(256) void k_matA(
    const u16* __restrict__ inh, const float* __restrict__ A,
    u16* __restrict__ outh)
{
    __shared__ float AL[50 * 52];
    __shared__ float inL[32 * 52];
    const int t = threadIdx.x;
    for (int e = t; e < 2500; e += 256) AL[(e / 50) * 52 + (e % 50)] = A[e];
    const long rbase = (long)blockIdx.x * 32;
    for (int e = t; e < 1600; e += 256) {
        int r = e / 50, j = e % 50;
        inL[r * 52 + j] = b2f(inh[(rbase + r) * 56 + j]);
    }
    __syncthreads();
    for (int item = t; item < 1600; item += 256) {
        int r = item / 50, kk = item % 50;
        float acc = 0.f;
#pragma unroll 10
        for (int j = 0; j < 50; ++j)
            acc += inL[r * 52 + j] * AL[j * 52 + kk];
        outh[(rbase + r) * 56 + kk] = f2b(acc);
    }
}

// ---------------------------------------------------------------------------
// xp2 MFMA GEMM: out[r][j] (fp32, stride 152) = dot(feats[r], W2[j]) + bih2[j]
// ---------------------------------------------------------------------------
__global__ __launch_bounds__(256) void k_xp2mm(
    const u16* __restrict__ feats, const u16* __restrict__ w2h,
    const float* __restrict__ bih2, float* __restrict__ out)
{
    __shared__ s16 Ab[2048];      // [kc4][row64][e8]
    __shared__ s16 Bb[2560];      // [kc4][col80][e8]
    __shared__ float bhL[160];
    const int t = threadIdx.x;
    const int w = t >> 6, l = t & 63, lg = l >> 4, lr = l & 15;
    const int mb = blockIdx.x >> 1, nb = blockIdx.x & 1;
    const long rowbase = (long)mb * 64;
    const int colbase = nb * 80;
    if (t < 160) bhL[t] = (t < 150) ? bih2[t] : 0.f;

    f32x4 acc[5];
#pragma unroll
    for (int i = 0; i < 5; ++i) acc[i] = (f32x4){0,0,0,0};

    for (int ch = 0; ch < 25; ++ch) {
        __syncthreads();
        {
            int kc = t >> 6, row = t & 63;
            *(short8v*)&Ab[t * 8] =
                *(const short8v*)(feats + (rowbase + row) * 800 + ch * 32 + kc * 8);
        }
        for (int it = t; it < 320; it += 256) {
            int kc = it / 80, col = it % 80;
            int gcol = colbase + col;
            short8v v = {0,0,0,0,0,0,0,0};
            if (gcol < 150)
                v = *(const short8v*)(w2h + (size_t)gcol * 800 + ch * 32 + kc * 8);
            *(short8v*)&Bb[it * 8] = v;
        }
        __syncthreads();
        short8v a = *(short8v*)&Ab[(lg * 64 + w * 16 + lr) * 8];
#pragma unroll
        for (int ct = 0; ct < 5; ++ct) {
            short8v bv = *(short8v*)&Bb[(lg * 80 + ct * 16 + lr) * 8];
            acc[ct] = __builtin_amdgcn_mfma_f32_16x16x32_bf16(a, bv, acc[ct], 0, 0, 0);
        }
    }
#pragma unroll
    for (int ct = 0; ct < 5; ++ct) {
        int gcol = colbase + ct * 16 + lr;
        if (gcol < 150) {
#pragma unroll
            for (int rr = 0; rr < 4; ++rr) {
                long row = rowbase + w * 16 + lg * 4 + rr;
                out[row * 152 + gcol] = acc[ct][rr] + bhL[gcol];
            }
        }
    }
}

// ---------------------------------------------------------------------------
// fc1 + fc2 + log_softmax + KL fused: one block per b.
// ---------------------------------------------------------------------------
__global__ __launch_bounds__(128) void k_head(
    const float* __restrict__ Hs, const float* __restrict__ w1,
    const float* __restrict__ b1, const float* __restrict__ w2,
    const float* __restrict__ b2, const float* __restrict__ y,
    float* __restrict__ partial)
{
    __shared__ float hr[700];
    __shared__ float hidL[100];
    const int t = threadIdx.x;
    const long b = blockIdx.x;
    for (int e = t; e < 700; e += 128) hr[e] = Hs[b * 700 + e];
    __syncthreads();
    if (t < 100) {
        float acc = b1[t];
        const float4* wp = (const float4*)(w1 + (size_t)t * 700);
        for (int k4 = 0; k4 < 175; ++k4) {
            float4 wv = wp[k4];
            float4 hv = *(float4*)&hr[k4 * 4];
            acc += wv.x * hv.x + wv.y * hv.y + wv.z * hv.z + wv.w * hv.w;
        }
        hidL[t] = fmaxf(acc, 0.f);
    }
    __syncthreads();
    if (t < 64) {
        float logit = -1e30f;
        if (t < 14) {
            logit = b2[t];
            for (int k = 0; k < 100; ++k) logit += hidL[k] * w2[t * 100 + k];
        }
        float m = logit;
        for (int off = 8; off; off >>= 1) m = fmaxf(m, __shfl_xor(m, off, 16));
        float ex = (t < 14) ? __expf(logit - m) : 0.f;
        float se = ex;
        for (int off = 8; off; off >>= 1) se += __shfl_xor(se, off, 16);
        float kl = 0.f;
        if (t < 14) {
            float lp = logit - m - __logf(se);
            float yv = y[b * 14 + t];
            kl = (yv > 0.f) ? yv * (__logf(yv) - lp) : 0.f;
        }
        for (int off = 8; off; off >>= 1) kl += __shfl_xor(kl, off, 16);
        if (t == 0) partial[b] = kl;
    }
}

__global__ __launch_bounds__(256) void k_reduce(
    const float* __restrict__ partial, float* __restrict__ out)
{
    __shared__ float sm[256];
    const int t = threadIdx.x;
    sm[t] = partial[t] + partial[t + 256] + partial[t + 512] + partial[t + 768];
    __syncthreads();
    for (int off = 128; off; off >>= 1) {
        if (t < off) sm[t] += sm[t + off];
        __syncthreads();
    }
    if (t == 0) out[0] = sm[0] * (1.f / 14336.f);
}

// ---------------------------------------------------------------------------
extern "C" void kernel_launch(void* const* d_in, const int* in_sizes, int n_in,
                              void* d_out, int out_size, void* d_ws, size_t ws_size,
                              hipStream_t stream)
{
    const int*   ctx_idx  = (const int*)d_in[0];
    const int*   cand_idx = (const int*)d_in[1];
    const float* y_dev    = (const float*)d_in[2];
    const float* emb      = (const float*)d_in[3];
    const float* A        = (const float*)d_in[4];
    const float* Wih_c    = (const float*)d_in[5];
    const float* Whh_c    = (const float*)d_in[6];
    const float* bih_c    = (const float*)d_in[7];
    const float* bhh_c    = (const float*)d_in[8];
    const float* Wih_r    = (const float*)d_in[9];
    const float* Whh_r    = (const float*)d_in[10];
    const float* bih_r    = (const float*)d_in[11];
    const float* bhh_r    = (const float*)d_in[12];
    const float* conv_w   = (const float*)d_in[13];
    const float* Wih2     = (const float*)d_in[14];
    const float* Whh2     = (const float*)d_in[15];
    const float* bih2     = (const float*)d_in[16];
    const float* bhh2     = (const float*)d_in[17];
    const float* fc1_w    = (const float*)d_in[18];
    const float* fc1_b    = (const float*)d_in[19];
    const float* fc2_w    = (const float*)d_in[20];
    const float* fc2_b    = (const float*)d_in[21];

    float* ws = (float*)d_ws;
    // Arena (float slots), total 28,734,128 f = 114.9 MB. All regions disjoint.
    u16*   embh    = (u16*)ws;               // [21128][200] bf16 = 2,112,800 f
    u16*   proj_ch = (u16*)(ws + 2112800);   // [21184][152] bf16 = 1,609,984 f
    u16*   proj_rh = (u16*)(ws + 3722784);   // [21184][152] bf16 = 1,609,984 f
    u16*   ctx_hh  = (u16*)(ws + 5332768);   // [32768][56] bf16 = 917,504 f
    u16*   ctxA_h  = (u16*)(ws + 6250272);   // [32768][56] bf16 = 917,504 f
    u16*   candh_h = (u16*)(ws + 7167776);   // [458752][56] bf16 = 12,845,056 f
    u16*   feats_h = (u16*)(ws + 20012832);  // [14336][800] bf16 = 5,734,400 f
    u16*   w2h     = (u16*)(ws + 25747232);  // [150][800] bf16 = 60,000 f
    u16*   wch     = (u16*)(ws + 25807232);  // [150][200] bf16 = 15,000 f
    u16*   wrh     = (u16*)(ws + 25822232);  // [150][200] bf16 = 15,000 f
    float* xp2     = ws + 25837232;          // [14336][152] = 2,179,072
    float* hs2     = ws + 28016304;          // 716,800
    float* part    = ws + 28733104;          // 1,024

    // 0. bf16 tables (one launch; w2h stored k-permuted)
    k_cvt_all <<<4654, 256, 0, stream>>>(emb, embh, Wih_c, wch, Wih_r, wrh,
                                         Wih2, w2h);
    // 1. both vocab projections (one launch, bih folded, bf16 out)
    k_projmm2 <<<1324, 256, 0, stream>>>(embh, wch, wrh, bih_c, bih_r,
                                         proj_ch, proj_rh, 21128);
    // 2. merged: GRU scans (960 blocks) + M1 match+conv+pool (7168 blocks)
    k_scan_m1 <<<8128, 256, 0, stream>>>(proj_ch, proj_rh, ctx_idx, cand_idx,
                                         Whh_c, Whh_r, bhh_c, bhh_r,
                                         ctx_hh, candh_h, embh, conv_w, feats_h);
    k_matA <<<1024, 256, 0, stream>>>(ctx_hh, A, ctxA_h);
    // 3. M2 match+conv+pool (slim LDS, 12 blocks/CU)
    k_m2conv <<<7168, 256, 0, stream>>>(ctxA_h, candh_h, conv_w, feats_h);
    // 4. accumulation GRU + fused head
    k_xp2mm <<<448, 256, 0, stream>>>(feats_h, w2h, bih2, xp2);
    k_scan2 <<<128, 256, 0, stream>>>(xp2, Whh2, bhh2, hs2);
    k_head <<<1024, 128, 0, stream>>>(hs2, fc1_w, fc1_b, fc2_w, fc2_b, y_dev, part);
    k_reduce <<<1, 256, 0, stream>>>(part, (float*)d_out);
}